// Round 2
// baseline (114.275 us; speedup 1.0000x reference)
//
#include <hip/hip_runtime.h>
#include <math.h>

#define NN 2048
#define CC 128
#define BTILE 16
#define NT 128
#define NCHUNK (NN / NT)   // 16
#define LI (NN / 64)       // 32
#define EPSF 1e-16f

__device__ __forceinline__ float wave_sum(float v) {
#pragma unroll
  for (int o = 32; o; o >>= 1) v += __shfl_xor(v, o, 64);
  return v;
}
__device__ __forceinline__ float wave_max(float v) {
#pragma unroll
  for (int o = 32; o; o >>= 1) v = fmaxf(v, __shfl_xor(v, o, 64));
  return v;
}
__device__ __forceinline__ float softplusf(float x) {
  return fmaxf(x, 0.0f) + log1pf(__expf(-fabsf(x)));
}

__global__ __launch_bounds__(256) void ntm_norm_kernel(const float* __restrict__ M,
                                                       float* __restrict__ mnorm) {
  int w = threadIdx.x >> 6, lane = threadIdx.x & 63;
  int row = blockIdx.x * 4 + w;
  float2 v = *(const float2*)&M[row * CC + 2 * lane];
  float s = wave_sum(v.x * v.x + v.y * v.y);
  if (lane == 0) mnorm[row] = sqrtf(s);
}

__global__ __launch_bounds__(256, 1) void ntm_main_kernel(
    const float* __restrict__ kptr, const float* __restrict__ beta_,
    const float* __restrict__ g_, const float* __restrict__ s_,
    const float* __restrict__ gamma_, const float* __restrict__ w_prev,
    const float* __restrict__ M, const float* __restrict__ mnorm,
    float* __restrict__ out) {
  __shared__ float mlds[NT][132];  // 128 rows x 132 floats (pad for banks)

  const int t = threadIdx.x;
  const int lane = t & 63;
  const int w = __builtin_amdgcn_readfirstlane(t >> 6);  // wave id, uniform
  const int b0 = blockIdx.x * BTILE;
  const int lanem1 = (lane + 63) & 63;
  const int lanep1 = (lane + 1) & 63;

  // ---- k row norms: wave handles rows b0+4w .. b0+4w+3 ----
  float kn[4];
#pragma unroll
  for (int rr = 0; rr < 4; ++rr) {
    float2 kv = *(const float2*)&kptr[(b0 + 4 * w + rr) * CC + 2 * lane];
    kn[rr] = sqrtf(wave_sum(kv.x * kv.x + kv.y * kv.y));
  }

  // wg[rr][li] holds, in sequence: dot -> logit -> exp -> w_g -> w_sharp
  // n index owned by (li, lane): n = 64*li + lane ; li = 2*chunk + nn
  float wg[4][LI];

#pragma unroll
  for (int ch = 0; ch < NCHUNK; ++ch) {
    __syncthreads();
    const int n0 = ch * NT;
    // stage 128 M-rows into LDS, coalesced float4
#pragma unroll
    for (int p = 0; p < 16; ++p) {
      int idx = p * 256 + t;
      int row = idx >> 5, c4 = idx & 31;
      *(float4*)&mlds[row][4 * c4] = *(const float4*)&M[(n0 + row) * CC + 4 * c4];
    }
    __syncthreads();

    float acc[4][2] = {{0.f, 0.f}, {0.f, 0.f}, {0.f, 0.f}, {0.f, 0.f}};
#pragma unroll 2
    for (int c4 = 0; c4 < 32; ++c4) {
      float4 m0 = *(const float4*)&mlds[lane][4 * c4];
      float4 m1 = *(const float4*)&mlds[lane + 64][4 * c4];
#pragma unroll
      for (int rr = 0; rr < 4; ++rr) {
        // wave-uniform address -> scalar loads (SGPR operand in the FMAs)
        float4 kv = *(const float4*)&kptr[(b0 + 4 * w + rr) * CC + 4 * c4];
        acc[rr][0] += kv.x * m0.x + kv.y * m0.y + kv.z * m0.z + kv.w * m0.w;
        acc[rr][1] += kv.x * m1.x + kv.y * m1.y + kv.z * m1.z + kv.w * m1.w;
      }
    }
#pragma unroll
    for (int rr = 0; rr < 4; ++rr) {
      wg[rr][2 * ch] = acc[rr][0];      // n = n0 + lane
      wg[rr][2 * ch + 1] = acc[rr][1];  // n = n0 + 64 + lane
    }
  }

#pragma unroll
  for (int rr = 0; rr < 4; ++rr) {
    const int r = b0 + 4 * w + rr;
    // per-row scalars (uniform addresses)
    const float betav = softplusf(beta_[r]);
    const float gv = 1.0f / (1.0f + __expf(-g_[r]));
    float sh0 = s_[3 * r], sh1 = s_[3 * r + 1], sh2 = s_[3 * r + 2];
    float shm = fmaxf(sh0, fmaxf(sh1, sh2));
    float e0 = __expf(sh0 - shm), e1 = __expf(sh1 - shm), e2 = __expf(sh2 - shm);
    float sdenom = 1.0f / (e0 + e1 + e2);
    sh0 = e0 * sdenom; sh1 = e1 * sdenom; sh2 = e2 * sdenom;
    const float gammav = 1.0f + softplusf(gamma_[r]);

    // logits + row max
    float mx = -3.4e38f;
#pragma unroll
    for (int li = 0; li < LI; ++li) {
      float mn = mnorm[64 * li + lane];
      float z = betav * (wg[rr][li] / (kn[rr] * mn + EPSF));
      wg[rr][li] = z;
      mx = fmaxf(mx, z);
    }
    mx = wave_max(mx);

    // exp + sum
    float se = 0.0f;
#pragma unroll
    for (int li = 0; li < LI; ++li) {
      float e = __expf(wg[rr][li] - mx);
      wg[rr][li] = e;
      se += e;
    }
    se = wave_sum(se);
    const float einv = 1.0f / se;

    // w_c -> w_g (stays in registers; neighbors exchanged via shuffles)
#pragma unroll
    for (int li = 0; li < LI; ++li) {
      float wc = wg[rr][li] * einv;
      float wp = w_prev[(size_t)r * NN + 64 * li + lane];
      wg[rr][li] = gv * wc + (1.0f - gv) * wp;
    }

    // circular conv via lane shuffles + sharpen.
    // w_g[n-1]: lane-1 same li; for lane 0 it is wg[li-1] from lane 63.
    // w_g[n+1]: lane+1 same li; for lane 63 it is wg[li+1] from lane 0.
    float a_prev = __shfl(wg[rr][LI - 1], lanem1, 64);  // A[31]
    float b_cur = __shfl(wg[rr][0], lanep1, 64);        // B[0]
    const float b_wrap = b_cur;                         // B[0] for li=31 wrap
    float sp = 0.0f;
#pragma unroll
    for (int li = 0; li < LI; ++li) {
      float a_cur = __shfl(wg[rr][li], lanem1, 64);
      float b_next = (li < LI - 1) ? __shfl(wg[rr][(li + 1) & (LI - 1)], lanep1, 64)
                                   : b_wrap;
      float pv = (lane == 0) ? a_prev : a_cur;
      float nx = (lane == 63) ? b_next : b_cur;
      float wt = sh0 * pv + sh1 * wg[rr][li] + sh2 * nx;
      float p = __expf(gammav * __logf(wt));  // wt>0; log(0)->-inf -> p=0 ok
      wg[rr][li] = p;
      sp += p;
      a_prev = a_cur;
      b_cur = b_next;
    }
    sp = wave_sum(sp);
    const float pinv = 1.0f / (sp + EPSF);

#pragma unroll
    for (int li = 0; li < LI; ++li) {
      out[(size_t)r * NN + 64 * li + lane] = wg[rr][li] * pinv;
    }
  }
}

extern "C" void kernel_launch(void* const* d_in, const int* in_sizes, int n_in,
                              void* d_out, int out_size, void* d_ws, size_t ws_size,
                              hipStream_t stream) {
  const float* k = (const float*)d_in[0];
  const float* beta = (const float*)d_in[1];
  const float* g = (const float*)d_in[2];
  const float* s = (const float*)d_in[3];
  const float* gamma = (const float*)d_in[4];
  const float* w_prev = (const float*)d_in[5];
  const float* M = (const float*)d_in[6];
  float* out = (float*)d_out;
  float* mnorm = (float*)d_ws;  // 2048 floats

  ntm_norm_kernel<<<NN / 4, 256, 0, stream>>>(M, mnorm);
  ntm_main_kernel<<<4096 / BTILE, 256, 0, stream>>>(k, beta, g, s, gamma,
                                                    w_prev, M, mnorm, out);
}